// Round 1
// baseline (260.313 us; speedup 1.0000x reference)
//
#include <hip/hip_runtime.h>
#include <hip/hip_bf16.h>

#define B_ 16
#define N_ 8192
#define C_ 512
#define H_ 8
#define HD_ 64

// ws float layout:
//   [0, 512)            qfull (cls@Wq * scale)
//   [512, 4608)         qk[h][c]  (8 x 512)
//   [4608, ...)         partials: per (b,chunk): { l[8], acc[8*512] } stride 4104

// ---------------- K1: qfull = cls @ Wq * HD^-0.5 ----------------
__global__ void k_qfull(const float* __restrict__ cls, const float* __restrict__ Wq,
                        float* __restrict__ ws) {
    __shared__ float red[256];
    int t = threadIdx.x;
    int o = blockIdx.x * 64 + (t & 63);
    int q = t >> 6;  // 0..3
    float p = 0.f;
    for (int c = q * 128; c < q * 128 + 128; ++c)
        p += cls[c] * Wq[c * C_ + o];
    red[t] = p;
    __syncthreads();
    if (t < 64) {
        float s = red[t] + red[t + 64] + red[t + 128] + red[t + 192];
        ws[o] = s * 0.125f;  // HD^-0.5 = 1/8
    }
}

// ---------------- K2: qk[h][c] = sum_d Wk[c, h*64+d] * qfull[h*64+d] ----------------
__global__ void k_qk(const float* __restrict__ Wk, float* __restrict__ ws) {
    __shared__ float wrow[8 * 520];  // 8 rows of Wk, padded stride
    __shared__ float qf[512];
    int t = threadIdx.x;
    int c0 = blockIdx.x * 8;
    int r = t >> 5;             // 8 rows, 32 threads each
    int col = (t & 31) * 16;    // 16 floats per thread
    const float4* src = (const float4*)(Wk + (size_t)(c0 + r) * C_ + col);
    float4* dst = (float4*)(&wrow[r * 520 + col]);
    dst[0] = src[0]; dst[1] = src[1]; dst[2] = src[2]; dst[3] = src[3];
    if (t < 128) ((float4*)qf)[t] = ((const float4*)ws)[t];
    __syncthreads();
    if (t < 64) {
        int h = t >> 3, cc = t & 7;
        const float* wr = &wrow[cc * 520 + h * 64];
        const float* qh = &qf[h * 64];
        float s = 0.f;
#pragma unroll
        for (int d = 0; d < 64; ++d) s += wr[d] * qh[d];
        ws[512 + h * C_ + c0 + cc] = s;
    }
}

// ---------------- K3: main streaming pass over x ----------------
__global__ __launch_bounds__(256) void k_main(const float* __restrict__ x,
                                              const float* __restrict__ ws,
                                              float* __restrict__ part, int CH) {
    int blk = blockIdx.x;
    int b = blk / CH, chunk = blk % CH;
    int lane = threadIdx.x & 63, wave = threadIdx.x >> 6;
    int rpb = N_ / CH;       // rows per block
    int rpw = rpb >> 2;      // rows per wave (4 waves)
    int n0 = chunk * rpb + wave * rpw;

    const float* qk = ws + 512;
    // qk fragments in registers: lane owns columns lane*8 .. lane*8+7
    float qr[8][8];
#pragma unroll
    for (int h = 0; h < 8; ++h) {
        float4 a = *(const float4*)(qk + h * C_ + lane * 8);
        float4 bb = *(const float4*)(qk + h * C_ + lane * 8 + 4);
        qr[h][0] = a.x;  qr[h][1] = a.y;  qr[h][2] = a.z;  qr[h][3] = a.w;
        qr[h][4] = bb.x; qr[h][5] = bb.y; qr[h][6] = bb.z; qr[h][7] = bb.w;
    }

    float acc[8][8];
#pragma unroll
    for (int h = 0; h < 8; ++h)
#pragma unroll
        for (int j = 0; j < 8; ++j) acc[h][j] = 0.f;
    float l[8] = {0.f, 0.f, 0.f, 0.f, 0.f, 0.f, 0.f, 0.f};

    const float* xrow = x + ((size_t)b * N_ + n0) * C_ + lane * 8;
    float4 c0 = *(const float4*)(xrow);
    float4 c1 = *(const float4*)(xrow + 4);

#pragma unroll 1
    for (int i = 0; i < rpw; ++i) {
        float4 p0, p1;
        if (i + 1 < rpw) {  // prefetch next row
            p0 = *(const float4*)(xrow + C_);
            p1 = *(const float4*)(xrow + C_ + 4);
        }
        xrow += C_;
        float xv[8] = {c0.x, c0.y, c0.z, c0.w, c1.x, c1.y, c1.z, c1.w};

        float p[8];
#pragma unroll
        for (int h = 0; h < 8; ++h) {
            float s = xv[0] * qr[h][0];
#pragma unroll
            for (int j = 1; j < 8; ++j) s += xv[j] * qr[h][j];
            p[h] = s;
        }
        // 6-stage butterfly reduce of all 8 head-partials across 64 lanes
#pragma unroll
        for (int st = 1; st < 64; st <<= 1) {
#pragma unroll
            for (int h = 0; h < 8; ++h) p[h] += __shfl_xor(p[h], st, 64);
        }
        // un-normalized softmax accumulate (logits are O(1); no max needed)
#pragma unroll
        for (int h = 0; h < 8; ++h) {
            float w = __expf(p[h]);
            l[h] += w;
#pragma unroll
            for (int j = 0; j < 8; ++j) acc[h][j] += w * xv[j];
        }
        c0 = p0; c1 = p1;
    }

    // block-combine the 4 waves' partials in LDS
    __shared__ float sacc[8 * 512];
    __shared__ float sl[8];
    for (int w = 0; w < 4; ++w) {
        if (wave == w) {
#pragma unroll
            for (int h = 0; h < 8; ++h) {
                float4 lo = {acc[h][0], acc[h][1], acc[h][2], acc[h][3]};
                float4 hi = {acc[h][4], acc[h][5], acc[h][6], acc[h][7]};
                float4* dst = (float4*)&sacc[h * C_ + lane * 8];
                if (w == 0) { dst[0] = lo; dst[1] = hi; }
                else {
                    float4 a0 = dst[0], a1 = dst[1];
                    a0.x += lo.x; a0.y += lo.y; a0.z += lo.z; a0.w += lo.w;
                    a1.x += hi.x; a1.y += hi.y; a1.z += hi.z; a1.w += hi.w;
                    dst[0] = a0; dst[1] = a1;
                }
            }
            if (lane == 0) {
#pragma unroll
                for (int h = 0; h < 8; ++h) {
                    if (w == 0) sl[h] = l[h]; else sl[h] += l[h];
                }
            }
        }
        __syncthreads();
    }

    float* pb = part + (size_t)blk * 4104;
    if (threadIdx.x < 8) pb[threadIdx.x] = sl[threadIdx.x];
    float* pa = pb + 8;
    for (int k = threadIdx.x; k < 4096; k += 256) pa[k] = sacc[k];
}

// ---------------- K4: merge partials, project through Wv then Wp ----------------
__global__ void k_merge(const float* __restrict__ part, const float* __restrict__ Wv,
                        const float* __restrict__ Wp, const float* __restrict__ bp,
                        float* __restrict__ out, int CH) {
    int b = blockIdx.x, t = threadIdx.x;
    __shared__ float aa[8 * 512];
    __shared__ float pl[512];
    __shared__ float Linv[8];
    const float* pb = part + (size_t)b * CH * 4104;

    if (t < 8) {
        float s = 0.f;
        for (int p = 0; p < CH; ++p) s += pb[(size_t)p * 4104 + t];
        Linv[t] = 1.f / s;
    }

    float s0[8], s1[8];
#pragma unroll
    for (int h = 0; h < 8; ++h) { s0[h] = 0.f; s1[h] = 0.f; }
    for (int p = 0; p < CH; ++p) {
        const float* pa = pb + (size_t)p * 4104 + 8;
#pragma unroll
        for (int h = 0; h < 8; ++h) {
            float2 v = *(const float2*)(pa + h * C_ + 2 * t);
            s0[h] += v.x; s1[h] += v.y;
        }
    }
    __syncthreads();
#pragma unroll
    for (int h = 0; h < 8; ++h) {
        aa[h * C_ + 2 * t]     = s0[h] * Linv[h];
        aa[h * C_ + 2 * t + 1] = s1[h] * Linv[h];
    }
    __syncthreads();

    // pooled[o] = sum_c aa[h(o)][c] * Wv[c,o]
#pragma unroll 1
    for (int oo = 0; oo < 2; ++oo) {
        int o = t + oo * 256;
        int h = o >> 6;
        const float* ah = &aa[h * C_];
        float s = 0.f;
        for (int c = 0; c < C_; ++c) s += ah[c] * Wv[(size_t)c * C_ + o];
        pl[o] = s;
    }
    __syncthreads();

    // out[b,o] = bp[o] + sum_c pl[c] * Wp[c,o]
#pragma unroll 1
    for (int oo = 0; oo < 2; ++oo) {
        int o = t + oo * 256;
        float s = bp[o];
        for (int c = 0; c < C_; ++c) s += pl[c] * Wp[(size_t)c * C_ + o];
        out[(size_t)b * C_ + o] = s;
    }
}

extern "C" void kernel_launch(void* const* d_in, const int* in_sizes, int n_in,
                              void* d_out, int out_size, void* d_ws, size_t ws_size,
                              hipStream_t stream) {
    const float* x   = (const float*)d_in[0];
    const float* cls = (const float*)d_in[1];
    const float* Wq  = (const float*)d_in[2];
    const float* Wk  = (const float*)d_in[3];
    const float* Wv  = (const float*)d_in[4];
    const float* Wp  = (const float*)d_in[5];
    const float* bp  = (const float*)d_in[6];
    float* out = (float*)d_out;
    float* ws  = (float*)d_ws;

    int CH = 64;  // chunks per batch row; shrink if workspace is small
    while (CH > 1 && (size_t)(4608 + (size_t)B_ * CH * 4104) * 4 > ws_size) CH >>= 1;

    k_qfull<<<8, 256, 0, stream>>>(cls, Wq, ws);
    k_qk<<<64, 256, 0, stream>>>(Wk, ws);
    k_main<<<B_ * CH, 256, 0, stream>>>(x, ws, ws + 4608, CH);
    k_merge<<<B_, 256, 0, stream>>>(ws + 4608, Wv, Wp, bp, out, CH);
}

// Round 2
// 181.040 us; speedup vs baseline: 1.4379x; 1.4379x over previous
//
#include <hip/hip_runtime.h>
#include <hip/hip_bf16.h>

#define B_ 16
#define N_ 8192
#define C_ 512
#define H_ 8
#define HD_ 64
#define CH_ 32

// ws float layout:
//   [0, 512)          qfull (cls@Wq * scale)
//   [512, 4608)       qk[h][c]  (8 x 512)
//   [4608, 4736)      Linv[b][h]  (16 x 8)
//   [4736, 70272)     aa[b][h][c] unnormalized weighted sums (16 x 8 x 512)
//   [70272, 86656)    pp[half][b][o] partial pooled (2 x 16 x 512)
//   [86656, ...)      partials: per (b,chunk): { l[8], acc[8*512] } stride 4104
#define WS_QK   512
#define WS_LINV 4608
#define WS_AA   4736
#define WS_PP   70272
#define WS_PART 86656

// ---------------- K1: qfull = cls @ Wq * HD^-0.5 ----------------
__global__ void k_qfull(const float* __restrict__ cls, const float* __restrict__ Wq,
                        float* __restrict__ ws) {
    __shared__ float red[256];
    int t = threadIdx.x;
    int o = blockIdx.x * 64 + (t & 63);
    int q = t >> 6;  // 0..3
    float p = 0.f;
    for (int c = q * 128; c < q * 128 + 128; ++c)
        p += cls[c] * Wq[c * C_ + o];
    red[t] = p;
    __syncthreads();
    if (t < 64) {
        float s = red[t] + red[t + 64] + red[t + 128] + red[t + 192];
        ws[o] = s * 0.125f;  // HD^-0.5 = 1/8
    }
}

// ---------------- K2: qk[h][c] = sum_d Wk[c, h*64+d] * qfull[h*64+d] ----------------
__global__ void k_qk(const float* __restrict__ Wk, float* __restrict__ ws) {
    __shared__ float wrow[8 * 520];  // 8 rows of Wk, padded stride
    __shared__ float qf[512];
    int t = threadIdx.x;
    int c0 = blockIdx.x * 8;
    int r = t >> 5;             // 8 rows, 32 threads each
    int col = (t & 31) * 16;    // 16 floats per thread
    const float4* src = (const float4*)(Wk + (size_t)(c0 + r) * C_ + col);
    float4* dst = (float4*)(&wrow[r * 520 + col]);
    dst[0] = src[0]; dst[1] = src[1]; dst[2] = src[2]; dst[3] = src[3];
    if (t < 128) ((float4*)qf)[t] = ((const float4*)ws)[t];
    __syncthreads();
    if (t < 64) {
        int h = t >> 3, cc = t & 7;
        const float* wr = &wrow[cc * 520 + h * 64];
        const float* qh = &qf[h * 64];
        float s = 0.f;
#pragma unroll
        for (int d = 0; d < 64; ++d) s += wr[d] * qh[d];
        ws[WS_QK + h * C_ + c0 + cc] = s;
    }
}

// ---------------- K3: main streaming pass over x ----------------
// Lane owns cols [4L,4L+4) and [256+4L,256+4L+4).
// Folded butterfly: after 6 stages lane holds full 64-lane logit sum for
// head f(lane)=4*b0+2*b1+b2 (bits of lane); src lane for head h is bitrev3(h).
__global__ __launch_bounds__(256, 2) void k_main(const float* __restrict__ x,
                                                 const float* __restrict__ ws,
                                                 float* __restrict__ part, int CH) {
    int blk = blockIdx.x;
    int b = blk / CH, chunk = blk % CH;
    int lane = threadIdx.x & 63, wave = threadIdx.x >> 6;
    int rpb = N_ / CH;       // rows per block
    int rpw = rpb >> 2;      // rows per wave (4 waves)
    int n0 = chunk * rpb + wave * rpw;

    const float* qk = ws + WS_QK;
    float qr[8][8];
#pragma unroll
    for (int h = 0; h < 8; ++h) {
        float4 a = *(const float4*)(qk + h * C_ + 4 * lane);
        float4 bb = *(const float4*)(qk + h * C_ + 256 + 4 * lane);
        qr[h][0] = a.x;  qr[h][1] = a.y;  qr[h][2] = a.z;  qr[h][3] = a.w;
        qr[h][4] = bb.x; qr[h][5] = bb.y; qr[h][6] = bb.z; qr[h][7] = bb.w;
    }

    float acc[8][8];
#pragma unroll
    for (int h = 0; h < 8; ++h)
#pragma unroll
        for (int j = 0; j < 8; ++j) acc[h][j] = 0.f;
    float lsum = 0.f;

    const float* xp = x + ((size_t)b * N_ + n0) * C_;
    int lo = 4 * lane, hi = 256 + 4 * lane;

    auto row_body = [&](float xv[8]) {
        float p[8];
#pragma unroll
        for (int h = 0; h < 8; ++h) {
            float s = xv[0] * qr[h][0];
#pragma unroll
            for (int j = 1; j < 8; ++j) s = fmaf(xv[j], qr[h][j], s);
            p[h] = s;
        }
        int b0 = lane & 1, b1 = lane & 2, b2 = lane & 4;
        float t4[4];
#pragma unroll
        for (int i = 0; i < 4; ++i) {
            float send = b0 ? p[i] : p[i + 4];
            float recv = __shfl_xor(send, 1, 64);
            t4[i] = (b0 ? p[i + 4] : p[i]) + recv;
        }
        float u2[2];
#pragma unroll
        for (int i = 0; i < 2; ++i) {
            float send = b1 ? t4[i] : t4[i + 2];
            float recv = __shfl_xor(send, 2, 64);
            u2[i] = (b1 ? t4[i + 2] : t4[i]) + recv;
        }
        float send = b2 ? u2[0] : u2[1];
        float recv = __shfl_xor(send, 4, 64);
        float v = (b2 ? u2[1] : u2[0]) + recv;
        v += __shfl_xor(v, 8, 64);
        v += __shfl_xor(v, 16, 64);
        v += __shfl_xor(v, 32, 64);
        float e = __expf(v);   // logits are O(1): un-normalized softmax is safe
        lsum += e;
#pragma unroll
        for (int h = 0; h < 8; ++h) {
            int src = ((h & 4) >> 2) | (h & 2) | ((h & 1) << 2);
            float wf = __int_as_float(__builtin_amdgcn_readlane(__float_as_int(e), src));
#pragma unroll
            for (int j = 0; j < 8; ++j) acc[h][j] = fmaf(wf, xv[j], acc[h][j]);
        }
    };

    // prefetch depth 4
    float4 R[4][2];
#pragma unroll
    for (int k = 0; k < 4; ++k) {
        R[k][0] = *(const float4*)(xp + (size_t)k * C_ + lo);
        R[k][1] = *(const float4*)(xp + (size_t)k * C_ + hi);
    }
#pragma unroll 1
    for (int i = 0; i < rpw; i += 4) {
#pragma unroll
        for (int k = 0; k < 4; ++k) {
            float xv[8] = {R[k][0].x, R[k][0].y, R[k][0].z, R[k][0].w,
                           R[k][1].x, R[k][1].y, R[k][1].z, R[k][1].w};
            int nf = i + k + 4; nf = nf < rpw ? nf : rpw - 1;  // clamped prefetch
            R[k][0] = *(const float4*)(xp + (size_t)nf * C_ + lo);
            R[k][1] = *(const float4*)(xp + (size_t)nf * C_ + hi);
            row_body(xv);
        }
    }

    // per-wave l values (uniform), then block-combine in LDS
    float lw[8];
#pragma unroll
    for (int h = 0; h < 8; ++h) {
        int src = ((h & 4) >> 2) | (h & 2) | ((h & 1) << 2);
        lw[h] = __int_as_float(__builtin_amdgcn_readlane(__float_as_int(lsum), src));
    }

    __shared__ float sacc[8 * 512];
    __shared__ float sl[8];
    for (int w = 0; w < 4; ++w) {
        if (wave == w) {
#pragma unroll
            for (int h = 0; h < 8; ++h) {
                float4 vlo = {acc[h][0], acc[h][1], acc[h][2], acc[h][3]};
                float4 vhi = {acc[h][4], acc[h][5], acc[h][6], acc[h][7]};
                float4* d0 = (float4*)&sacc[h * C_ + lo];
                float4* d1 = (float4*)&sacc[h * C_ + hi];
                if (w == 0) { d0[0] = vlo; d1[0] = vhi; }
                else {
                    float4 a0 = d0[0], a1 = d1[0];
                    a0.x += vlo.x; a0.y += vlo.y; a0.z += vlo.z; a0.w += vlo.w;
                    a1.x += vhi.x; a1.y += vhi.y; a1.z += vhi.z; a1.w += vhi.w;
                    d0[0] = a0; d1[0] = a1;
                }
            }
            if (lane == 0) {
#pragma unroll
                for (int h = 0; h < 8; ++h) {
                    if (w == 0) sl[h] = lw[h]; else sl[h] += lw[h];
                }
            }
        }
        __syncthreads();
    }

    float* pb = part + (size_t)blk * 4104;
    if (threadIdx.x < 8) pb[threadIdx.x] = sl[threadIdx.x];
    float* pa = pb + 8;
    for (int k = threadIdx.x; k < 4096; k += 256) pa[k] = sacc[k];
}

// ---------------- K4: reduce partials -> aa (unnormalized), Linv ----------------
__global__ void k_reduce(const float* __restrict__ part, float* __restrict__ ws, int CH) {
    int b = blockIdx.x >> 4, cc = blockIdx.x & 15, t = threadIdx.x;
    int h = t >> 5, c = cc * 32 + (t & 31);
    const float* pb = part + (size_t)b * CH * 4104;
    float s = 0.f;
    for (int p = 0; p < CH; ++p) s += pb[(size_t)p * 4104 + 8 + h * C_ + c];
    ws[WS_AA + b * 4096 + h * C_ + c] = s;
    if (cc == 0 && t < 8) {
        float ls = 0.f;
        for (int p = 0; p < CH; ++p) ls += pb[(size_t)p * 4104 + t];
        ws[WS_LINV + b * 8 + t] = 1.f / ls;
    }
}

// ---------------- K5: pooled (c-split halves) = Linv * aa @ Wv ----------------
__global__ void k_proj1(const float* __restrict__ ws, const float* __restrict__ Wv,
                        float* __restrict__ pp) {
    int gid = blockIdx.x * 256 + threadIdx.x;  // [0, 16384)
    int half = gid >> 13;
    int r = gid & 8191;
    int b = r >> 9, o = r & 511, h = o >> 6;
    const float* aa = ws + WS_AA + b * 4096 + h * C_;
    float Li = ws[WS_LINV + b * 8 + h];
    int c0 = half * 256;
    float s = 0.f;
#pragma unroll 8
    for (int c = 0; c < 256; ++c)
        s = fmaf(aa[c0 + c], Wv[(size_t)(c0 + c) * C_ + o], s);
    pp[half * 8192 + r] = s * Li;
}

// ---------------- K6: out = pooled @ Wp + bp ----------------
__global__ void k_proj2(const float* __restrict__ ws, const float* __restrict__ Wp,
                        const float* __restrict__ bp, float* __restrict__ out) {
    int gid = blockIdx.x * 256 + threadIdx.x;  // [0, 8192)
    int b = gid >> 9, o = gid & 511;
    const float* pp = ws + WS_PP + b * 512;
    float s = bp[o];
#pragma unroll 8
    for (int c = 0; c < 512; ++c) {
        float pc = pp[c] + pp[8192 + c];
        s = fmaf(pc, Wp[(size_t)c * C_ + o], s);
    }
    out[(size_t)b * C_ + o] = s;
}

extern "C" void kernel_launch(void* const* d_in, const int* in_sizes, int n_in,
                              void* d_out, int out_size, void* d_ws, size_t ws_size,
                              hipStream_t stream) {
    const float* x   = (const float*)d_in[0];
    const float* cls = (const float*)d_in[1];
    const float* Wq  = (const float*)d_in[2];
    const float* Wk  = (const float*)d_in[3];
    const float* Wv  = (const float*)d_in[4];
    const float* Wp  = (const float*)d_in[5];
    const float* bp  = (const float*)d_in[6];
    float* out = (float*)d_out;
    float* ws  = (float*)d_ws;

    int CH = CH_;
    while (CH > 1 && (size_t)(WS_PART + (size_t)B_ * CH * 4104) * 4 > ws_size) CH >>= 1;

    k_qfull<<<8, 256, 0, stream>>>(cls, Wq, ws);
    k_qk<<<64, 256, 0, stream>>>(Wk, ws);
    k_main<<<B_ * CH, 256, 0, stream>>>(x, ws, ws + WS_PART, CH);
    k_reduce<<<B_ * 16, 256, 0, stream>>>(ws + WS_PART, ws, CH);
    k_proj1<<<64, 256, 0, stream>>>(ws, Wv, ws + WS_PP);
    k_proj2<<<32, 256, 0, stream>>>(ws, Wp, bp, out);
}